// Round 7
// baseline (132.188 us; speedup 1.0000x reference)
//
#include <hip/hip_runtime.h>

// SSIM (window=3, stride=3, pad=1) on (16,3,512,512) fp32 -> scalar mean.
// V7 = V6 + NON-TEMPORAL image loads.
// Theory: per replay the harness fills 256 MiB of d_ws with 0xAA (41us fill,
// floods all of L3 with dirty lines, evicts inputs). Main's reads then evict
// dirty fill lines -> ~100MB writeback concurrent with our 100MB read ->
// ~200MB HBM traffic ~= 31us, matching the stuck ~34us across V5/V6.
// Non-temporal loads don't allocate in L2/L3 -> no evictions -> pure read.

#define HW       512
#define PLANE_SZ (HW * HW)
#define OHW      171                    // (512 + 2 - 3)/3 + 1
#define NPLANE   48                     // 16 batch * 3 channels
#define NOUT     (NPLANE * OHW * OHW)   // 1,403,568
#define NTASK    (NPLANE * OHW * 2)     // 16416 half-row wave-tasks
#define TPB      256
#define WPB      4
#define NBLK     (NTASK / WPB)          // 4104 (exact)

typedef float f4 __attribute__((ext_vector_type(4)));

__device__ __forceinline__ float ssim_val(float s1, float s2, float s11,
                                          float s22, float s12) {
  const float C1 = 1e-4f, C2 = 9e-4f;
  const float m11 = s1 * s1, m22 = s2 * s2, m12 = s1 * s2;
  const float sg1 = s11 - m11, sg2 = s22 - m22, sg12 = s12 - m12;
  const float num = (2.0f * m12 + C1) * (2.0f * sg12 + C2);
  const float den = (m11 + m22 + C1) * (sg1 + sg2 + C2);
  return num * __builtin_amdgcn_rcpf(den);   // rel err ~1e-7 << 2.4e-4 thr
}

__global__ __launch_bounds__(TPB) void ssim_main(
    const float* __restrict__ img1, const float* __restrict__ img2,
    const float* __restrict__ win, float* __restrict__ partial) {
  const int lane = threadIdx.x & 63;
  const int wv   = threadIdx.x >> 6;
  const int task = blockIdx.x * WPB + wv;      // < 16416 (grid exact)
  const int plane = task / (2 * OHW);
  const int rem   = task - plane * (2 * OHW);
  const int oy    = rem >> 1;
  const int h     = rem & 1;                   // half: cols 256h..256h+255

  // Separable window: w[3r+c] = wy[r]*wx[c].
  float wy[3], wx[3];
#pragma unroll
  for (int k = 0; k < 3; ++k) {
    wy[k] = win[3 * k] + win[3 * k + 1] + win[3 * k + 2];
    wx[k] = win[k] + win[k + 3] + win[k + 6];
  }
  const int r0 = 3 * oy - 1;
  float wyv[3];
  wyv[0] = (r0 >= 0) ? wy[0] : 0.0f;           // oy==0: zero-weight top row
  wyv[1] = wy[1];
  wyv[2] = wy[2];
  const int rr0 = (r0 < 0) ? 0 : r0;

  const float* a = img1 + (size_t)plane * PLANE_SZ;
  const float* b = img2 + (size_t)plane * PLANE_SZ;

  // ---- load phase: non-temporal (no L2/L3 allocation) ----
  f4 xa[3], xb[3], pa[3], pb[3];
#pragma unroll
  for (int k = 0; k < 3; ++k) {
    const int r = (k == 0) ? rr0 : (r0 + k);
    const f4* ra = (const f4*)(a + (size_t)r * HW);
    const f4* rb = (const f4*)(b + (size_t)r * HW);
    const int s = 64 * h + lane;
    xa[k] = __builtin_nontemporal_load(ra + s);
    xb[k] = __builtin_nontemporal_load(rb + s);
    if (h) {                                    // uniform branch per wave
      pa[k] = __builtin_nontemporal_load(ra + 63);  // cols 252..255 (bcast)
      pb[k] = __builtin_nontemporal_load(rb + 63);
    } else {
      pa[k] = (f4){0.f, 0.f, 0.f, 0.f};         // left pad: virtual zeros
      pb[k] = (f4){0.f, 0.f, 0.f, 0.f};
    }
  }

  // ---- row collapse (lane f4) ----
  float P1[4] = {0,0,0,0}, P2[4] = {0,0,0,0}, P11[4] = {0,0,0,0},
        P22[4] = {0,0,0,0}, P12[4] = {0,0,0,0};
#pragma unroll
  for (int k = 0; k < 3; ++k) {
    const float wyk = wyv[k];
#pragma unroll
    for (int j = 0; j < 4; ++j) {
      const float x = xa[k][j], y = xb[k][j];
      const float u = wyk * x, v = wyk * y;
      P1[j] += u;  P2[j] += v;
      P11[j] = fmaf(u, x, P11[j]);
      P22[j] = fmaf(v, y, P22[j]);
      P12[j] = fmaf(u, y, P12[j]);
    }
  }

  // m for this lane's f4 (c0 = 256h + 4*lane; 256%3==1): m=(h+lane)%3
  const int m = (h + lane) % 3;
  // col c0+j uses wx[(c0+j+1)%3] = wx[(m+j+1)%3]
  float wxl[4];
#pragma unroll
  for (int j = 0; j < 4; ++j) {
    const int ix = (m + j + 1) % 3;
    wxl[j] = (ix == 0) ? wx[0] : ((ix == 1) ? wx[1] : wx[2]);
  }
  // left-mask: m==0 ->{1,1,0,0}, m==1 ->{1,0,0,0}, m==2 ->{1,1,1,0}
  const float aL = (m != 1) ? 1.0f : 0.0f;
  const float bL = (m == 2) ? 1.0f : 0.0f;

  float L[5], R[5];
  {
    float t0, t1, t2, t3, full, left;
#define BIN(Q, PP)                                             \
    t0 = wxl[0] * PP[0]; t1 = wxl[1] * PP[1];                  \
    t2 = wxl[2] * PP[2]; t3 = wxl[3] * PP[3];                  \
    full = (t0 + t1) + (t2 + t3);                              \
    left = fmaf(bL, t2, fmaf(aL, t1, t0));                     \
    L[Q] = left; R[Q] = full - left;
    BIN(0, P1) BIN(1, P2) BIN(2, P11) BIN(3, P22) BIN(4, P12)
#undef BIN
  }

  // ---- R_prev: right partial of the straddling f4 (cols 256h-4..256h-1),
  // uniform across lanes. m' = (256h-4)%3 = (h+2)%3.
  float Rp[5] = {0.f, 0.f, 0.f, 0.f, 0.f};
  if (h) {                                      // uniform branch
    float Q1[4] = {0,0,0,0}, Q2[4] = {0,0,0,0}, Q11[4] = {0,0,0,0},
          Q22[4] = {0,0,0,0}, Q12[4] = {0,0,0,0};
#pragma unroll
    for (int k = 0; k < 3; ++k) {
      const float wyk = wyv[k];
#pragma unroll
      for (int j = 0; j < 4; ++j) {
        const float x = pa[k][j], y = pb[k][j];
        const float u = wyk * x, v = wyk * y;
        Q1[j] += u;  Q2[j] += v;
        Q11[j] = fmaf(u, x, Q11[j]);
        Q22[j] = fmaf(v, y, Q22[j]);
        Q12[j] = fmaf(u, y, Q12[j]);
      }
    }
    const int mp = (h + 2) % 3;                 // == 0 for h==1
    float wxp[4];
#pragma unroll
    for (int j = 0; j < 4; ++j) {
      const int ix = (mp + j + 1) % 3;
      wxp[j] = (ix == 0) ? wx[0] : ((ix == 1) ? wx[1] : wx[2]);
    }
    const float aP = (mp != 1) ? 1.0f : 0.0f;
    const float bP = (mp == 2) ? 1.0f : 0.0f;
    float t0, t1, t2, t3, full, left;
#define BINP(Q, PP)                                            \
    t0 = wxp[0] * PP[0]; t1 = wxp[1] * PP[1];                  \
    t2 = wxp[2] * PP[2]; t3 = wxp[3] * PP[3];                  \
    full = (t0 + t1) + (t2 + t3);                              \
    left = fmaf(bP, t2, fmaf(aP, t1, t0));                     \
    Rp[Q] = full - left;
    BINP(0, Q1) BINP(1, Q2) BINP(2, Q11) BINP(3, Q22) BINP(4, Q12)
#undef BINP
  }

  // ---- merge: L takes previous lane's R when incomplete (m != 2);
  // lane 0's "previous" is Rp (zeros for h==0 -> also the left pad).
  const float allow = (m != 2) ? 1.0f : 0.0f;
#pragma unroll
  for (int q = 0; q < 5; ++q) {
    float up = __shfl_up(R[q], 1, 64);
    if (lane == 0) up = Rp[q];
    L[q] = fmaf(allow, up, L[q]);
  }

  // ---- finalize: L always owned; R owned iff m == 1 (complete in-lane) ----
  float acc = ssim_val(L[0], L[1], L[2], L[3], L[4]);
  if (m == 1) acc += ssim_val(R[0], R[1], R[2], R[3], R[4]);

  // wave reduce -> LDS -> one write per block (proven pattern)
#pragma unroll
  for (int off = 32; off > 0; off >>= 1) acc += __shfl_down(acc, off, 64);
  __shared__ float wsum[TPB / 64];
  if (lane == 0) wsum[wv] = acc;
  __syncthreads();
  if (threadIdx.x == 0) {
    float s = 0.f;
#pragma unroll
    for (int i = 0; i < TPB / 64; ++i) s += wsum[i];
    partial[blockIdx.x] = s;   // every block writes its slot: no init needed
  }
}

__global__ __launch_bounds__(256) void ssim_final(
    const float* __restrict__ partial, float* __restrict__ out) {
  double acc = 0.0;
  for (int i = threadIdx.x; i < NBLK; i += 256) acc += (double)partial[i];
#pragma unroll
  for (int off = 32; off > 0; off >>= 1) acc += __shfl_down(acc, off, 64);
  __shared__ double wsum[4];
  const int lane = threadIdx.x & 63, wid = threadIdx.x >> 6;
  if (lane == 0) wsum[wid] = acc;
  __syncthreads();
  if (threadIdx.x == 0) {
    double s = 0.0;
#pragma unroll
    for (int i = 0; i < 4; ++i) s += wsum[i];
    out[0] = (float)(s / (double)NOUT);
  }
}

extern "C" void kernel_launch(void* const* d_in, const int* in_sizes, int n_in,
                              void* d_out, int out_size, void* d_ws, size_t ws_size,
                              hipStream_t stream) {
  const float* img1 = (const float*)d_in[0];
  const float* img2 = (const float*)d_in[1];
  const float* win  = (const float*)d_in[2];
  float* partial = (float*)d_ws;   // NBLK floats
  float* out = (float*)d_out;

  ssim_main<<<NBLK, TPB, 0, stream>>>(img1, img2, win, partial);
  ssim_final<<<1, 256, 0, stream>>>(partial, out);
}

// Round 8
// 120.070 us; speedup vs baseline: 1.1009x; 1.1009x over previous
//
#include <hip/hip_runtime.h>

// SSIM (window=3, stride=3, pad=1) on (16,3,512,512) fp32 -> scalar mean.
// V8 = V5 (best, 119.9us total) + GRID-LEVEL SOFTWARE PREFETCH.
// Post-mortems: R3 counters show main fetches only ~65MB (36MB L3-hit), no
// writeback storm (WRITE_SIZE=45KB) -> memory floor ~10-12us, yet V5/V6 sit
// at ~33us with nothing saturated; V6's +50% vmem instrs changed nothing.
// Hypothesis: cold-miss latency on small block bursts. Fix: block b issues
// 3 dword loads/thread (1 per 64B line) covering block b+512's 48KB working
// set; results sunk via asm volatile at kernel END (no early waitcnt). L3 is
// chip-level, so later blocks run L3-hot. NT loads (V7) reverted: regressed.

#define HW       512
#define PLANE_SZ (HW * HW)
#define OHW      171                    // (512 + 2 - 3)/3 + 1
#define NPLANE   48                     // 16 batch * 3 channels
#define NOUT     (NPLANE * OHW * OHW)   // 1,403,568
#define NTASK    (NPLANE * OHW)         // 8208 wave-tasks
#define TPB      256
#define WPB      4                      // waves per block
#define NBLK     (NTASK / WPB)          // 2052 (exact)
#define PFD      512                    // prefetch distance in blocks

typedef float f4 __attribute__((ext_vector_type(4)));

__device__ __forceinline__ float ssim_val(float s1, float s2, float s11,
                                          float s22, float s12) {
  const float C1 = 1e-4f, C2 = 9e-4f;
  const float m11 = s1 * s1, m22 = s2 * s2, m12 = s1 * s2;
  const float sg1 = s11 - m11, sg2 = s22 - m22, sg12 = s12 - m12;
  return ((2.0f * m12 + C1) * (2.0f * sg12 + C2)) /
         ((m11 + m22 + C1) * (sg1 + sg2 + C2));
}

__global__ __launch_bounds__(TPB) void ssim_main(
    const float* __restrict__ img1, const float* __restrict__ img2,
    const float* __restrict__ win, float* __restrict__ partial) {
  const int lane  = threadIdx.x & 63;
  const int wv    = threadIdx.x >> 6;
  const int task  = blockIdx.x * WPB + wv;     // < 8208 always (grid exact)
  const int plane = task / OHW;
  const int oy    = task - plane * OHW;

  // Separable weights: w[3r+c] = wy[r]*wx[c] (window = outer(g,g)).
  float wy[3], wx[3];
#pragma unroll
  for (int k = 0; k < 3; ++k) {
    wy[k] = win[3 * k] + win[3 * k + 1] + win[3 * k + 2];
    wx[k] = win[k] + win[k + 3] + win[k + 6];
  }
  const int r0 = 3 * oy - 1;                   // top window row (pad=1)
  float wyv[3];
  wyv[0] = (r0 >= 0) ? wy[0] : 0.0f;           // oy==0: zero-weight top row
  wyv[1] = wy[1];
  wyv[2] = wy[2];
  const int rr0 = (r0 < 0) ? 0 : r0;

  const float* a = img1 + (size_t)plane * PLANE_SZ;
  const float* b = img2 + (size_t)plane * PLANE_SZ;

  // ---- 12 fully-coalesced float4 wave-loads (16B lane stride) ----
  f4 xa[3][2], xb[3][2];
#pragma unroll
  for (int k = 0; k < 3; ++k) {
    const int r = (k == 0) ? rr0 : (r0 + k);   // rows 3oy..3oy+1 always valid
    const f4* ra = (const f4*)(a + (size_t)r * HW);
    const f4* rb = (const f4*)(b + (size_t)r * HW);
    xa[k][0] = ra[lane];      xa[k][1] = ra[lane + 64];
    xb[k][0] = rb[lane];      xb[k][1] = rb[lane + 64];
  }

  // ---- prefetch block (blockIdx.x + PFD)'s working set into chip-level L3:
  // one dword per 64B line; 3 loads/lane cover 192 lines = 6 rows x 2KB.
  // Results consumed only by asm at kernel end -> no waitcnt before compute.
  float pf0 = 0.f, pf1 = 0.f, pf2 = 0.f;
  {
    const int ptask = (blockIdx.x + PFD) * WPB + wv;
    if (ptask < NTASK) {
      const int pplane = ptask / OHW;
      const int poy    = ptask - pplane * OHW;
      const int pr0    = 3 * poy - 1;
      const int prr0   = (pr0 < 0) ? 0 : pr0;
      const float* pA = img1 + (size_t)pplane * PLANE_SZ;
      const float* pB = img2 + (size_t)pplane * PLANE_SZ;
      float acc3[3];
#pragma unroll
      for (int i = 0; i < 3; ++i) {
        const int t   = 64 * i + lane;         // 0..191
        const int seg = t >> 5;                // 0..5
        const int img = seg & 1;
        const int k   = seg >> 1;
        const int r   = (k == 0) ? prr0 : (pr0 + k);
        const float* base = img ? pB : pA;
        acc3[i] = base[(size_t)r * HW + (size_t)(t & 31) * 16];
      }
      pf0 = acc3[0]; pf1 = acc3[1]; pf2 = acc3[2];
    }
  }

  float acc = 0.0f;
  float fwd[5];                                // chunk-A right partials (seam)

#pragma unroll
  for (int c = 0; c < 2; ++c) {
    // chunk start col c0 = 256*c + 4*lane; m = c0 % 3 (256 % 3 == 1)
    const int m = (lane + c) % 3;

    // ---- row collapse with wy ----
    float P1[4]  = {0.f, 0.f, 0.f, 0.f};
    float P2[4]  = {0.f, 0.f, 0.f, 0.f};
    float P11[4] = {0.f, 0.f, 0.f, 0.f};
    float P22[4] = {0.f, 0.f, 0.f, 0.f};
    float P12[4] = {0.f, 0.f, 0.f, 0.f};
#pragma unroll
    for (int k = 0; k < 3; ++k) {
      const float wyk = wyv[k];
#pragma unroll
      for (int j = 0; j < 4; ++j) {
        const float x = xa[k][c][j];
        const float y = xb[k][c][j];
        const float u = wyk * x;
        const float v = wyk * y;
        P1[j] += u;
        P2[j] += v;
        P11[j] = fmaf(u, x, P11[j]);
        P22[j] = fmaf(v, y, P22[j]);
        P12[j] = fmaf(u, y, P12[j]);
      }
    }

    // ---- column weights: col c0+j has wx index (m+j+1)%3 ----
    float wxl[4];
#pragma unroll
    for (int j = 0; j < 4; ++j) {
      const int ix = (m + j + 1) % 3;
      wxl[j] = (ix == 0) ? wx[0] : ((ix == 1) ? wx[1] : wx[2]);
    }

    // ---- bin split: left-mask by m: m==0 ->{1,1,0,0}, 1->{1,0,0,0}, 2->{1,1,1,0}
    const float aL = (m != 1) ? 1.0f : 0.0f;
    const float bL = (m == 2) ? 1.0f : 0.0f;
    float L[5], R[5];
    {
      float t0, t1, t2, t3, full, left;
#define BIN(Q, P)                                              \
      t0 = wxl[0] * P[0]; t1 = wxl[1] * P[1];                  \
      t2 = wxl[2] * P[2]; t3 = wxl[3] * P[3];                  \
      full = (t0 + t1) + (t2 + t3);                            \
      left = fmaf(bL, t2, fmaf(aL, t1, t0));                   \
      L[Q] = left; R[Q] = full - left;
      BIN(0, P1) BIN(1, P2) BIN(2, P11) BIN(3, P22) BIN(4, P12)
#undef BIN
    }
    if (c == 0) {
#pragma unroll
      for (int q = 0; q < 5; ++q) fwd[q] = R[q];
    }

    // ---- merge: L-bin takes previous lane's R when incomplete (m != 2) ----
    const float allow =
        (m != 2 && !(c == 0 && lane == 0)) ? 1.0f : 0.0f;  // lane0 A: left pad
#pragma unroll
    for (int q = 0; q < 5; ++q) {
      float up = __shfl_up(R[q], 1, 64);
      if (c == 1) {
        const float seam = __shfl(fwd[q], 63, 64);  // chunk-A lane63 R
        up = (lane == 0) ? seam : up;
      }
      L[q] = fmaf(allow, up, L[q]);
    }

    // ---- finalize: L-bin always owned; R-bin owned iff m == 1 ----
    const float mR = (m == 1) ? 1.0f : 0.0f;
    acc += ssim_val(L[0], L[1], L[2], L[3], L[4]);
    acc += mR * ssim_val(R[0], R[1], R[2], R[3], R[4]);
  }

  // sink the prefetch results (keeps loads alive; waited only here, at end)
  asm volatile("" :: "v"(pf0), "v"(pf1), "v"(pf2));

  // wave(64) shuffle reduce -> LDS -> one write per block (proven pattern)
#pragma unroll
  for (int off = 32; off > 0; off >>= 1) acc += __shfl_down(acc, off, 64);
  __shared__ float wsum[TPB / 64];
  if (lane == 0) wsum[wv] = acc;
  __syncthreads();
  if (threadIdx.x == 0) {
    float s = 0.f;
#pragma unroll
    for (int i = 0; i < TPB / 64; ++i) s += wsum[i];
    partial[blockIdx.x] = s;   // every block writes its slot: no init needed
  }
}

__global__ __launch_bounds__(256) void ssim_final(
    const float* __restrict__ partial, float* __restrict__ out) {
  double acc = 0.0;
  for (int i = threadIdx.x; i < NBLK; i += 256) acc += (double)partial[i];
#pragma unroll
  for (int off = 32; off > 0; off >>= 1) acc += __shfl_down(acc, off, 64);
  __shared__ double wsum[4];
  const int lane = threadIdx.x & 63, wid = threadIdx.x >> 6;
  if (lane == 0) wsum[wid] = acc;
  __syncthreads();
  if (threadIdx.x == 0) {
    double s = 0.0;
#pragma unroll
    for (int i = 0; i < 4; ++i) s += wsum[i];
    out[0] = (float)(s / (double)NOUT);
  }
}

extern "C" void kernel_launch(void* const* d_in, const int* in_sizes, int n_in,
                              void* d_out, int out_size, void* d_ws, size_t ws_size,
                              hipStream_t stream) {
  const float* img1 = (const float*)d_in[0];
  const float* img2 = (const float*)d_in[1];
  const float* win  = (const float*)d_in[2];
  float* partial = (float*)d_ws;   // NBLK floats
  float* out = (float*)d_out;

  ssim_main<<<NBLK, TPB, 0, stream>>>(img1, img2, win, partial);
  ssim_final<<<1, 256, 0, stream>>>(partial, out);
}

// Round 9
// 119.367 us; speedup vs baseline: 1.1074x; 1.0059x over previous
//
#include <hip/hip_runtime.h>

// SSIM (window=3, stride=3, pad=1) on (16,3,512,512) fp32 -> scalar mean.
// V9 = V5 compute (proven, absmax 0.0) + INTRA-WAVE SOFTWARE PIPELINING.
// V5-V8 post-mortems: all variants are latency-bound with a bursty per-wave
// profile (12 loads -> full-latency stall -> ~700cyc compute -> retire);
// occupancy (V6), NT (V7), cross-block prefetch (V8) all neutral/regressed.
// Here each wave runs 4 consecutive row-tasks with ping-pong register sets:
// task t+1's 12 loads are issued BEFORE task t's compute consumes its data,
// so the compiler emits vmcnt(12)-style partial waits and the memory pipe
// always has the next 12KB queued. 2052 waves / 513 blocks -> all waves
// resident in one generation (~3 waves/SIMD at ~146 VGPR).

#define HW       512
#define PLANE_SZ (HW * HW)
#define OHW      171                    // (512 + 2 - 3)/3 + 1
#define NPLANE   48                     // 16 batch * 3 channels
#define NOUT     (NPLANE * OHW * OHW)   // 1,403,568
#define NTASK    (NPLANE * OHW)         // 8208 row-tasks
#define TPW      4                      // tasks per wave (8208 = 2052*4)
#define NWAVE    (NTASK / TPW)          // 2052
#define TPB      256
#define WPB      4
#define NBLK     (NWAVE / WPB)          // 513 (exact)

typedef float f4 __attribute__((ext_vector_type(4)));

struct TD { f4 xa[3][2]; f4 xb[3][2]; };   // one row-task's data (12 f4)

__device__ __forceinline__ float ssim_val(float s1, float s2, float s11,
                                          float s22, float s12) {
  const float C1 = 1e-4f, C2 = 9e-4f;
  const float m11 = s1 * s1, m22 = s2 * s2, m12 = s1 * s2;
  const float sg1 = s11 - m11, sg2 = s22 - m22, sg12 = s12 - m12;
  const float num = (2.0f * m12 + C1) * (2.0f * sg12 + C2);
  const float den = (m11 + m22 + C1) * (sg1 + sg2 + C2);
  return num * __builtin_amdgcn_rcpf(den);   // rel err ~1e-7 << 2.4e-4 thr
}

__device__ __forceinline__ void load_task(const float* __restrict__ img1,
                                          const float* __restrict__ img2,
                                          int task, int lane, TD& d) {
  const int plane = task / OHW;
  const int oy    = task - plane * OHW;
  const int r0    = 3 * oy - 1;
  const int rr0   = (r0 < 0) ? 0 : r0;
  const float* a = img1 + (size_t)plane * PLANE_SZ;
  const float* b = img2 + (size_t)plane * PLANE_SZ;
#pragma unroll
  for (int k = 0; k < 3; ++k) {
    const int r = (k == 0) ? rr0 : (r0 + k);
    const f4* ra = (const f4*)(a + (size_t)r * HW);
    const f4* rb = (const f4*)(b + (size_t)r * HW);
    d.xa[k][0] = ra[lane];      d.xa[k][1] = ra[lane + 64];
    d.xb[k][0] = rb[lane];      d.xb[k][1] = rb[lane + 64];
  }
}

__device__ __forceinline__ float task_ssim(const TD& d, int oy, int lane,
                                           float wy0, float wy1, float wy2,
                                           float wx0, float wx1, float wx2) {
  float wyv[3];
  wyv[0] = (oy == 0) ? 0.0f : wy0;             // top pad: zero-weight row 0
  wyv[1] = wy1;
  wyv[2] = wy2;

  float acc = 0.0f;
  float fwd[5];
#pragma unroll
  for (int c = 0; c < 2; ++c) {
    // chunk start col c0 = 256*c + 4*lane; m = c0 % 3 (256 % 3 == 1)
    const int m = (lane + c) % 3;

    float P1[4]  = {0.f, 0.f, 0.f, 0.f};
    float P2[4]  = {0.f, 0.f, 0.f, 0.f};
    float P11[4] = {0.f, 0.f, 0.f, 0.f};
    float P22[4] = {0.f, 0.f, 0.f, 0.f};
    float P12[4] = {0.f, 0.f, 0.f, 0.f};
#pragma unroll
    for (int k = 0; k < 3; ++k) {
      const float wyk = wyv[k];
#pragma unroll
      for (int j = 0; j < 4; ++j) {
        const float x = d.xa[k][c][j];
        const float y = d.xb[k][c][j];
        const float u = wyk * x;
        const float v = wyk * y;
        P1[j] += u;
        P2[j] += v;
        P11[j] = fmaf(u, x, P11[j]);
        P22[j] = fmaf(v, y, P22[j]);
        P12[j] = fmaf(u, y, P12[j]);
      }
    }

    float wxl[4];
#pragma unroll
    for (int j = 0; j < 4; ++j) {
      const int ix = (m + j + 1) % 3;
      wxl[j] = (ix == 0) ? wx0 : ((ix == 1) ? wx1 : wx2);
    }

    const float aL = (m != 1) ? 1.0f : 0.0f;
    const float bL = (m == 2) ? 1.0f : 0.0f;
    float L[5], R[5];
    {
      float t0, t1, t2, t3, full, left;
#define BIN(Q, P)                                              \
      t0 = wxl[0] * P[0]; t1 = wxl[1] * P[1];                  \
      t2 = wxl[2] * P[2]; t3 = wxl[3] * P[3];                  \
      full = (t0 + t1) + (t2 + t3);                            \
      left = fmaf(bL, t2, fmaf(aL, t1, t0));                   \
      L[Q] = left; R[Q] = full - left;
      BIN(0, P1) BIN(1, P2) BIN(2, P11) BIN(3, P22) BIN(4, P12)
#undef BIN
    }
    if (c == 0) {
#pragma unroll
      for (int q = 0; q < 5; ++q) fwd[q] = R[q];
    }

    const float allow =
        (m != 2 && !(c == 0 && lane == 0)) ? 1.0f : 0.0f;  // lane0 A: left pad
#pragma unroll
    for (int q = 0; q < 5; ++q) {
      float up = __shfl_up(R[q], 1, 64);
      if (c == 1) {
        const float seam = __shfl(fwd[q], 63, 64);  // chunk-A lane63 R
        up = (lane == 0) ? seam : up;
      }
      L[q] = fmaf(allow, up, L[q]);
    }

    const float mR = (m == 1) ? 1.0f : 0.0f;
    acc += ssim_val(L[0], L[1], L[2], L[3], L[4]);
    acc += mR * ssim_val(R[0], R[1], R[2], R[3], R[4]);
  }
  return acc;
}

__global__ __launch_bounds__(TPB, 3) void ssim_main(
    const float* __restrict__ img1, const float* __restrict__ img2,
    const float* __restrict__ win, float* __restrict__ partial) {
  const int lane = threadIdx.x & 63;
  const int wv   = threadIdx.x >> 6;
  const int wave = blockIdx.x * WPB + wv;      // 0..2051 (grid exact)
  const int base = wave * TPW;                 // 4 consecutive row-tasks

  // Separable window: w[3r+c] = wy[r]*wx[c] (window = outer(g,g)).
  float wy[3], wx[3];
#pragma unroll
  for (int k = 0; k < 3; ++k) {
    wy[k] = win[3 * k] + win[3 * k + 1] + win[3 * k + 2];
    wx[k] = win[k] + win[k + 3] + win[k + 6];
  }

  TD cur, nxt;
  load_task(img1, img2, base, lane, cur);      // prologue loads

  float acc = 0.0f;
#pragma unroll
  for (int t = 0; t < TPW; ++t) {
    if (t + 1 < TPW)
      load_task(img1, img2, base + t + 1, lane, nxt);  // issue BEFORE consume
    const int task  = base + t;
    const int plane = task / OHW;
    const int oy    = task - plane * OHW;
    acc += task_ssim(cur, oy, lane, wy[0], wy[1], wy[2], wx[0], wx[1], wx[2]);
    if (t + 1 < TPW) cur = nxt;                // SSA rename after full unroll
  }

  // wave(64) shuffle reduce -> LDS -> one write per block (proven pattern)
#pragma unroll
  for (int off = 32; off > 0; off >>= 1) acc += __shfl_down(acc, off, 64);
  __shared__ float wsum[TPB / 64];
  if (lane == 0) wsum[wv] = acc;
  __syncthreads();
  if (threadIdx.x == 0) {
    float s = 0.f;
#pragma unroll
    for (int i = 0; i < TPB / 64; ++i) s += wsum[i];
    partial[blockIdx.x] = s;   // every block writes its slot: no init needed
  }
}

__global__ __launch_bounds__(256) void ssim_final(
    const float* __restrict__ partial, float* __restrict__ out) {
  double acc = 0.0;
  for (int i = threadIdx.x; i < NBLK; i += 256) acc += (double)partial[i];
#pragma unroll
  for (int off = 32; off > 0; off >>= 1) acc += __shfl_down(acc, off, 64);
  __shared__ double wsum[4];
  const int lane = threadIdx.x & 63, wid = threadIdx.x >> 6;
  if (lane == 0) wsum[wid] = acc;
  __syncthreads();
  if (threadIdx.x == 0) {
    double s = 0.0;
#pragma unroll
    for (int i = 0; i < 4; ++i) s += wsum[i];
    out[0] = (float)(s / (double)NOUT);
  }
}

extern "C" void kernel_launch(void* const* d_in, const int* in_sizes, int n_in,
                              void* d_out, int out_size, void* d_ws, size_t ws_size,
                              hipStream_t stream) {
  const float* img1 = (const float*)d_in[0];
  const float* img2 = (const float*)d_in[1];
  const float* win  = (const float*)d_in[2];
  float* partial = (float*)d_ws;   // NBLK floats
  float* out = (float*)d_out;

  ssim_main<<<NBLK, TPB, 0, stream>>>(img1, img2, win, partial);
  ssim_final<<<1, 256, 0, stream>>>(partial, out);
}